// Round 7
// baseline (380.252 us; speedup 1.0000x reference)
//
#include <hip/hip_runtime.h>

// Fold (col2im): x (8, 32, 8, 8, 4096) f32, kernel (8,8), stride (4,4),
// patch grid 64x64 -> out (8, 32, 260, 260) f32.
//
// Round-5 lesson: occupancy 2->5 blocks/CU gained only ~7 us. Remaining
// theory: every block's stage->__syncthreads path drains vmcnt(0) (compiler
// emits full waitcnt before s_barrier), so each block serializes
// stage -> full-HBM-latency drain -> compute, and the read pipe has dead
// windows. Fix = T3/T4 pattern: persistent double-buffered blocks with
// counted vmcnt and raw s_barrier -- next tile's loads stay in flight
// through the current tile's compute; vmcnt never drains to 0 in the loop.
//
// Structure: 1024 blocks, one per (bc, r); r outer in the grid so all four
// r-writers of a bc share an XCD (output lines straddling row boundaries
// combine in one L2). Each block runs 8 tiles (T=0..7) of 8 output rows
// (ip = 8T..8T+7). LDS = 2 buffers x 32 KB. Per tile, 16 chunks x 2 KB:
//   chunk p   : rows 8T..8T+7   of A[p] = x[bc, r,   p, :, :]
//   chunk 8+p : rows 8T-1..8T+6 of B[p] = x[bc, r+4, p, :, :]
// (B chunk for T=0 starts at the previous plane's row 63 -- globally
// in-bounds since di=r+4>=4 -- and is masked by the ip>=1 predicate.)
//
// Per-wave vmcnt ledger (issue order: loads(T)[8], stores(T-1)[3],
// loads(T+1)[8]): s_waitcnt vmcnt(8) after issuing stage(T+1) retires
// everything through loads(T) and leaves loads(T+1) in flight. Raw
// s_barrier (no compiler drain) aligns waves; end-of-iter barrier protects
// buf[T&1] before stage(T+2) overwrites it.
//
// Compute math per output row h = 4*ip + r, w = 4k + s (verified in R5):
//   out = A[s][ip][k] + B[s][ip-1][k] + A[s+4][ip][k-1] + B[s+4][ip-1][k-1]
// Thread t: ii = t>>5 (row), ug = t&31 -> output float4s k = 2ug, 2ug+1
// (+ tail k=64 at ug==31). Row ip=64 (h=256+r, hi kernel row only) done
// directly after the loop.
//
// (Round 6 was an infra failure -- container died twice, no counters.
// Kernel audited for bounds/barrier/vmcnt correctness and resubmitted
// unchanged for a clean measurement.)

#define L      4096
#define H_OUT  260

typedef float vfloat4 __attribute__((ext_vector_type(4)));

__global__ __launch_bounds__(256) void fold_kernel(const float* __restrict__ x,
                                                   float* __restrict__ out) {
    __shared__ float lds[16384];   // 2 x 32 KB buffers (8192 floats each)

    int bid = blockIdx.x;          // 0..1023
    int bc  = bid & 255;           // fastest -> spreads reads across XCDs
    int r   = bid >> 8;            // all r of one bc share bid%8 -> same XCD

    int t    = threadIdx.x;
    int lane = t & 63;
    int wv   = t >> 6;

    auto stage = [&](int T, int buf) {
        #pragma unroll
        for (int ci = 0; ci < 4; ++ci) {
            int c   = 4 * wv + ci;     // 0..15
            int isB = c >> 3;
            int p   = c & 7;
            int di  = r + 4 * isB;
            long gb = ((long)(bc * 64 + di * 8 + p)) * L + (long)(8 * T - isB) * 64;
            const float* gp = x + gb + lane * 4;
            float* lp = lds + buf * 8192 + c * 512;
            #pragma unroll
            for (int k = 0; k < 2; ++k) {
                __builtin_amdgcn_global_load_lds(
                    (const __attribute__((address_space(1))) void*)(gp + k * 256),
                    (__attribute__((address_space(3))) void*)(lp + k * 256),
                    16, 0, 0);
            }
        }
    };

    stage(0, 0);                   // prologue

    int ii   = t >> 5;             // 0..7 (row within tile)
    int ug   = t & 31;             // k = 2ug, 2ug+1
    bool odd = (ug & 1);
    int  f   = ug >> 1;            // input float4 index 0..15

    const vfloat4 vz = {0.f, 0.f, 0.f, 0.f};

    for (int T = 0; T < 8; ++T) {
        if (T < 7) {
            stage(T + 1, (T + 1) & 1);
            asm volatile("s_waitcnt vmcnt(8)" ::: "memory");
        } else {
            asm volatile("s_waitcnt vmcnt(0)" ::: "memory");
        }
        __builtin_amdgcn_s_barrier();

        const vfloat4* l4 = (const vfloat4*)(lds + (T & 1) * 8192);
        int ip = 8 * T + ii;       // 0..63
        bool bvalid = (ip >= 1);

        vfloat4 o0, o1, tl;
        #pragma unroll
        for (int s = 0; s < 4; ++s) {
            int ai  = s * 128 + ii * 16 + f;          // A[s]
            int bi  = 1024 + ai;                      // B[s]
            int ahi = (s + 4) * 128 + ii * 16 + f;    // A[s+4]
            int bhi = 1024 + ahi;                     // B[s+4]

            vfloat4 alo = l4[ai];
            vfloat4 blo = bvalid ? l4[bi] : vz;
            vfloat4 ahc = l4[ahi];
            vfloat4 bhc = bvalid ? l4[bhi] : vz;
            float ap3 = (!odd && ug > 0) ? l4[ahi - 1][3] : 0.f;
            float bp3 = (!odd && ug > 0 && bvalid) ? l4[bhi - 1][3] : 0.f;

            float lo0 = odd ? (alo[2] + blo[2]) : (alo[0] + blo[0]);
            float hi0 = odd ? (ahc[1] + bhc[1]) : (ap3 + bp3);
            float lo1 = odd ? (alo[3] + blo[3]) : (alo[1] + blo[1]);
            float hi1 = odd ? (ahc[2] + bhc[2]) : (ahc[0] + bhc[0]);

            o0[s] = lo0 + hi0;
            o1[s] = lo1 + hi1;
            tl[s] = ahc[3] + bhc[3];                  // u = 63 (ug==31 only)
        }

        long orow = ((long)(bc * H_OUT) + (4 * ip + r)) * H_OUT;
        vfloat4* op = (vfloat4*)(out + orow);
        op[2 * ug + 0] = o0;
        op[2 * ug + 1] = o1;
        if (ug == 31) op[64] = tl;                    // w = 256..259

        __builtin_amdgcn_s_barrier();                 // protect buf[T&1]
    }

    // ---- extra row ip=64 (h = 256+r): hi kernel row only ----
    if (t < 65) {
        int u = t;
        const float* pb = x + ((long)(bc * 64 + (r + 4) * 8)) * L + 63 * 64;
        vfloat4 v;
        #pragma unroll
        for (int s = 0; s < 4; ++s) {
            float lo = (u <= 63) ? pb[(long)s * L + u] : 0.f;
            float hi = (u >= 1) ? pb[(long)(s + 4) * L + u - 1] : 0.f;
            v[s] = lo + hi;
        }
        ((vfloat4*)(out + ((long)(bc * H_OUT) + 256 + r) * H_OUT))[u] = v;
    }
}

extern "C" void kernel_launch(void* const* d_in, const int* in_sizes, int n_in,
                              void* d_out, int out_size, void* d_ws, size_t ws_size,
                              hipStream_t stream) {
    const float* x = (const float*)d_in[0];
    float* out     = (float*)d_out;

    // 1024 blocks = 256 bc x 4 r, 256 threads, 64 KB LDS, 2 blocks/CU.
    fold_kernel<<<1024, 256, 0, stream>>>(x, out);
}